// Round 1
// baseline (30135.873 us; speedup 1.0000x reference)
//
#include <hip/hip_runtime.h>
#include <hip/hip_fp16.h>

// Problem constants
#define NSTEP 512   // LP
#define NL    512   // LQ
#define NB    24
#define NH    150
#define KBLK  8     // blocks per batch-group
#define TMAIN 512   // threads per main block

// ---- ws layout (float offsets) ----
#define OFF_WUQA   (0u)                              // [b][l][h] 24*512*150
#define OFF_WUPALL (OFF_WUQA   + 24u*512u*150u)      // [i][b][h] 512*24*150
#define OFF_WQST   (OFF_WUPALL + 512u*24u*150u)      // [d][h] 150*150
#define OFF_WPST   (OFF_WQST   + 22500u)
#define OFF_WVT    (OFF_WPST   + 22500u)             // [h'][h] 150*150
#define OFF_G1T    (OFF_WVT    + 22500u)             // [d][j'] 150*300
#define OFF_G2T    (OFF_G1T    + 45000u)
#define OFF_WIHT   (OFF_G2T    + 45000u)             // [d'][j] 300*450
#define OFF_WHHT   (OFF_WIHT   + 135000u)            // [h'][j] 150*450
#define OFF_S      (OFF_WHHT   + 67500u)             // [b][l] 24*512
#define OFF_CP     (OFF_S      + 12288u)             // [k][b][152]
#define OFF_GH     (OFF_CP     + 8u*24u*152u)        // [b][456]
#define OFF_GI     (OFF_GH     + 24u*456u)           // [k][b][456]
#define OFF_BAR    (OFF_GI     + 8u*24u*456u)        // 800 uints: [0]=global, [32+b*32]=group
#define WS_FLOATS  (OFF_BAR + 800u)

__device__ __forceinline__ float fast_rcp(float x) { return __builtin_amdgcn_rcpf(x); }

__device__ __forceinline__ float fast_tanh(float x) {
  x = fminf(10.f, fmaxf(-10.f, x));
  float e = __expf(2.f * x);
  return (e - 1.f) * fast_rcp(e + 1.f);
}

__device__ __forceinline__ float fast_sigmoid(float x) {
  x = fminf(30.f, fmaxf(-30.f, x));
  return fast_rcp(1.f + __expf(-x));
}

// Tree barrier across the whole 192-block grid: 24 group counters -> 1 global.
// Monotonic counters (no reset); gen advances by 24 per barrier.
__device__ __forceinline__ void grid_barrier(unsigned* bar, int b, unsigned& gen) {
  __syncthreads();
  if (threadIdx.x == 0) {
    gen += 24u;
    unsigned prev = __hip_atomic_fetch_add(&bar[32 + b * 32], 1u,
                                           __ATOMIC_ACQ_REL, __HIP_MEMORY_SCOPE_AGENT);
    if ((prev & 7u) == 7u) {
      __hip_atomic_fetch_add(&bar[0], 1u, __ATOMIC_ACQ_REL, __HIP_MEMORY_SCOPE_AGENT);
    }
    while (__hip_atomic_load(&bar[0], __ATOMIC_RELAXED, __HIP_MEMORY_SCOPE_AGENT) < gen) {
      __builtin_amdgcn_s_sleep(2);
    }
    (void)__hip_atomic_load(&bar[0], __ATOMIC_ACQUIRE, __HIP_MEMORY_SCOPE_AGENT);
  }
  __syncthreads();
}

// ---------- prep: collapsed/transposed weights + barrier zeroing ----------
__global__ void prep_weights(const float* __restrict__ Wq, const float* __restrict__ Wp,
                             const float* __restrict__ Wv, const float* __restrict__ Wg,
                             const float* __restrict__ w_ih, const float* __restrict__ w_hh,
                             float* __restrict__ ws) {
  float* wqsT = ws + OFF_WQST;
  float* wpsT = ws + OFF_WPST;
  float* wvT  = ws + OFF_WVT;
  float* g1T  = ws + OFF_G1T;
  float* g2T  = ws + OFF_G2T;
  float* wihT = ws + OFF_WIHT;
  float* whhT = ws + OFF_WHHT;
  unsigned* bar = (unsigned*)(ws + OFF_BAR);

  int idx = blockIdx.x * blockDim.x + threadIdx.x;
  int n = gridDim.x * blockDim.x;

  for (int i = idx; i < 800; i += n) bar[i] = 0u;

  for (int i = idx; i < 150 * 150; i += n) {
    int d = i / 150, h = i - d * 150;
    wqsT[i] = Wq[h * 300 + d] + Wq[h * 300 + d + 150];
    wpsT[i] = Wp[h * 300 + d] + Wp[h * 300 + d + 150];
    wvT[i]  = Wv[h * 150 + d];
  }
  for (int i = idx; i < 150 * 300; i += n) {
    int d = i / 300, j = i - d * 300;
    int row = (300 + j) * 600;
    g1T[i] = Wg[row + d] + Wg[row + d + 150];        // up-part of collapsed Wg
    g2T[i] = Wg[row + 300 + d] + Wg[row + 450 + d];  // c-part
  }
  for (int i = idx; i < 300 * 450; i += n) {
    int d = i / 450, j = i - d * 450;
    wihT[i] = w_ih[j * 300 + d];
  }
  for (int i = idx; i < 150 * 450; i += n) {
    int d = i / 450, j = i - d * 450;
    whhT[i] = w_hh[j * 150 + d];
  }
}

// out = x(l,b,:150) @ wT  (wT is [d][h]); mode 0 -> [b][l][h], mode 1 -> [l][b][h]
__global__ __launch_bounds__(192) void prep_gemm(const float* __restrict__ x,
                                                 const float* __restrict__ wT,
                                                 float* __restrict__ outp, int mode) {
  const int l = blockIdx.x, b = blockIdx.y;
  __shared__ float sx[152];
  const int tid = threadIdx.x;
  if (tid < 150) sx[tid] = x[((size_t)l * 24 + b) * 150 + tid];
  __syncthreads();
  if (tid < 150) {
    float acc = 0.f;
    for (int d = 0; d < 150; ++d) acc += sx[d] * wT[d * 150 + tid];
    if (mode == 0) outp[((size_t)b * 512 + l) * 150 + tid] = acc;
    else           outp[((size_t)l * 24 + b) * 150 + tid] = acc;
  }
}

// ---------- main persistent kernel: 24 groups x 8 blocks ----------
__global__ __launch_bounds__(TMAIN) void pq_main(
    const float* __restrict__ up, const float* __restrict__ uq,
    const float* __restrict__ v0, const float* __restrict__ Vfull,
    const float* __restrict__ b_ih, const float* __restrict__ b_hh,
    float* __restrict__ ws, float* __restrict__ out) {
  const int tid = threadIdx.x;
  const int gid = blockIdx.x;
  const int b = gid % 24;   // group: all 8 blocks of b land on XCD b%8
  const int k = gid / 24;   // 0..7, owns l-chunk [k*64, k*64+64)

  const float* wuqa   = ws + OFF_WUQA;
  const float* wupall = ws + OFF_WUPALL;
  const float* wvT    = ws + OFF_WVT;
  const float* g1T    = ws + OFF_G1T;
  const float* g2T    = ws + OFF_G2T;
  const float* wihT   = ws + OFF_WIHT;
  const float* whhT   = ws + OFF_WHHT;
  float* ws_s  = ws + OFF_S;
  float* ws_cp = ws + OFF_CP;
  float* ws_gh = ws + OFF_GH;
  float* ws_gi = ws + OFF_GI;
  unsigned* bar = (unsigned*)(ws + OFF_BAR);

  __shared__ __half sWUq[64 * 150];  // own l-chunk of WUq (resident all 512 steps)
  __shared__ __half sUq[64 * 150];   // own l-chunk of uq
  __shared__ float sV[152];          // Vv
  __shared__ float sVl[152];         // v state (redundant per block)
  __shared__ float sY[152];          // Wup_i + Wvv
  __shared__ float sYp[304];
  __shared__ float sUp[152];         // up_i
  __shared__ float sC[152];          // combined c150
  __shared__ float sA[64];           // softmax weights for own chunk
  __shared__ float sGI[456];
  __shared__ float sGH[456];
  __shared__ float sCp[40];          // own c_ range
  __shared__ float sRed[16];
  __shared__ float sGHp[232];

  // INIT: stage chunks into LDS (once)
  {
    const float* src = wuqa + ((size_t)b * 512 + (size_t)k * 64) * 150;
    for (int idx = tid; idx < 64 * 150; idx += TMAIN) sWUq[idx] = __float2half(src[idx]);
    for (int idx = tid; idx < 64 * 150; idx += TMAIN) {
      int l = idx / 150, d = idx - l * 150;
      sUq[idx] = __float2half(uq[((k * 64 + l) * 24 + b) * 150 + d]);
    }
    for (int h = tid; h < 150; h += TMAIN) sV[h] = Vfull[b * 150 + h];
  }
  __syncthreads();

  unsigned gen = 0;

  for (int i = 0; i <= NSTEP; ++i) {
    // ---- P0: finalize previous step (gates), then y = Wup_i + v@Wv^T, gh ----
    if (i == 0) {
      if (tid < 150) sVl[tid] = v0[b * 150 + tid];
    } else {
      if (tid < 450) {
        float acc = b_ih[tid];
        #pragma unroll
        for (int kk = 0; kk < 8; ++kk) acc += ws_gi[(kk * 24 + b) * 456 + tid];
        sGI[tid] = acc;
        sGH[tid] = ws_gh[b * 456 + tid];
      }
    }
    __syncthreads();
    if (i > 0 && tid < 150) {
      const int h = tid;
      float rg = fast_sigmoid(sGI[h] + sGH[h]);
      float zg = fast_sigmoid(sGI[150 + h] + sGH[150 + h]);
      float nn = fast_tanh(sGI[300 + h] + rg * sGH[300 + h]);
      float vn = (1.f - zg) * nn + zg * sVl[h];
      sVl[h] = vn;
      if (k == 0) out[((size_t)(i - 1) * 24 + b) * 150 + h] = vn;
    }
    __syncthreads();
    if (i == NSTEP) break;

    // y partials (redundant per block) + load up_i
    if (tid < 300) {
      const int h = tid >> 1, half = tid & 1;
      const int hp0 = half * 75;
      float acc = 0.f;
      for (int hp = hp0; hp < hp0 + 75; ++hp) acc += sVl[hp] * wvT[hp * 150 + h];
      sYp[tid] = acc;
    } else if (tid >= 320 && tid < 470) {
      sUp[tid - 320] = up[((size_t)i * 24 + b) * 150 + (tid - 320)];
    }
    __syncthreads();
    // combine y; gh = v_i @ w_hh^T for own j-range (57 per block)
    if (tid < 150) {
      sY[tid] = wupall[((size_t)i * 24 + b) * 150 + tid] + sYp[2 * tid] + sYp[2 * tid + 1];
    } else if (tid >= 256 && tid < 484) {
      const int idx = tid - 256;
      const int q = idx / 57, jl = idx - q * 57;
      const int j = k * 57 + jl;
      float acc = 0.f;
      if (j < 450) {
        const int h1 = q * 38;
        const int h2 = (h1 + 38 < 150) ? h1 + 38 : 150;
        for (int hp = h1; hp < h2; ++hp) acc += sVl[hp] * whhT[hp * 450 + j];
      }
      sGHp[idx] = acc;
    }
    __syncthreads();
    if (tid < 57) {
      const int j = k * 57 + tid;
      if (j < 450)
        ws_gh[b * 456 + j] = sGHp[tid] + sGHp[57 + tid] + sGHp[114 + tid] + sGHp[171 + tid] + b_hh[j];
    }

    // ---- P1: s[b,l] = sum_h Vv[h]*tanh(WUq[l,h] + y[h]) for own 64 l's ----
    {
      const int w = tid >> 6, lane = tid & 63;
      for (int ll = w * 8; ll < w * 8 + 8; ++ll) {
        float acc = 0.f;
        for (int h = lane; h < 150; h += 64) {
          float arg = __half2float(sWUq[ll * 150 + h]) + sY[h];
          acc += sV[h] * fast_tanh(arg);
        }
        #pragma unroll
        for (int off = 32; off; off >>= 1) acc += __shfl_xor(acc, off, 64);
        if (lane == 0) ws_s[b * 512 + k * 64 + ll] = acc;
      }
    }
    grid_barrier(bar, b, gen);  // BAR1: s complete

    // ---- P2: softmax (redundant) + c-partial over own l-chunk ----
    {
      float sv = ws_s[b * 512 + tid];
      float m = sv;
      #pragma unroll
      for (int off = 32; off; off >>= 1) m = fmaxf(m, __shfl_xor(m, off, 64));
      if ((tid & 63) == 0) sRed[tid >> 6] = m;
      __syncthreads();
      m = sRed[0];
      #pragma unroll
      for (int w2 = 1; w2 < 8; ++w2) m = fmaxf(m, sRed[w2]);
      __syncthreads();
      float e = __expf(sv - m);
      float zs = e;
      #pragma unroll
      for (int off = 32; off; off >>= 1) zs += __shfl_xor(zs, off, 64);
      if ((tid & 63) == 0) sRed[tid >> 6] = zs;
      __syncthreads();
      zs = 0.f;
      #pragma unroll
      for (int w2 = 0; w2 < 8; ++w2) zs += sRed[w2];
      float a = e * fast_rcp(zs);
      if (tid >= k * 64 && tid < k * 64 + 64) sA[tid - k * 64] = a;
      __syncthreads();
      if (tid < 150) {
        float acc = 0.f;
        for (int ll = 0; ll < 64; ++ll) acc += sA[ll] * __half2float(sUq[ll * 150 + tid]);
        ws_cp[(k * 24 + b) * 152 + tid] = acc;
      }
    }
    grid_barrier(bar, b, gen);  // BAR2: c partials complete

    // ---- P3: combine c, g (own 38 j'), c_, gi-partials over own d-range ----
    {
      if (tid < 150) {
        float acc = 0.f;
        #pragma unroll
        for (int kk = 0; kk < 8; ++kk) acc += ws_cp[(kk * 24 + b) * 152 + tid];
        sC[tid] = acc;
      }
      __syncthreads();
      if (tid < 152) {
        const int jl = tid >> 2, qq = tid & 3;
        const int jp = k * 38 + jl;
        float acc = 0.f;
        if (jp < 300) {
          const float* W = (qq < 2) ? g1T : g2T;
          const float* X = (qq < 2) ? sUp : sC;
          const int d0 = (qq & 1) * 75;
          for (int d = d0; d < d0 + 75; ++d) acc += X[d] * W[d * 300 + jp];
        }
        sGHp[tid] = acc;
      }
      __syncthreads();
      if (tid < 38) {
        const int jp = k * 38 + tid;
        float cv = 0.f;
        if (jp < 300) {
          float x = sGHp[4 * tid] + sGHp[4 * tid + 1] + sGHp[4 * tid + 2] + sGHp[4 * tid + 3];
          float gg = fast_sigmoid(x);
          const int cidx = (jp >= 150) ? jp - 150 : jp;
          cv = gg * sC[cidx];
        }
        sCp[tid] = cv;
      }
      __syncthreads();
      if (tid < 450) {
        const int nd = (k < 7) ? 38 : 34;  // 300 - 7*38
        const int d0 = k * 38;
        float acc = 0.f;
        for (int dd = 0; dd < nd; ++dd) acc += sCp[dd] * wihT[(d0 + dd) * 450 + tid];
        ws_gi[(k * 24 + b) * 456 + tid] = acc;
      }
    }
    grid_barrier(bar, b, gen);  // BAR3: gi partials complete
  }
}

extern "C" void kernel_launch(void* const* d_in, const int* in_sizes, int n_in,
                              void* d_out, int out_size, void* d_ws, size_t ws_size,
                              hipStream_t stream) {
  const float* up   = (const float*)d_in[0];
  const float* uq   = (const float*)d_in[1];
  const float* v0   = (const float*)d_in[2];
  const float* V    = (const float*)d_in[3];
  const float* Wp   = (const float*)d_in[4];
  const float* Wq   = (const float*)d_in[5];
  const float* Wv   = (const float*)d_in[6];
  const float* Wg   = (const float*)d_in[7];
  const float* w_ih = (const float*)d_in[8];
  const float* w_hh = (const float*)d_in[9];
  const float* b_ih = (const float*)d_in[10];
  const float* b_hh = (const float*)d_in[11];
  float* ws  = (float*)d_ws;
  float* out = (float*)d_out;

  if (ws_size < (size_t)WS_FLOATS * sizeof(float)) {
    // Not enough scratch: bail (will show as validation failure, not corruption).
    return;
  }

  prep_weights<<<256, 256, 0, stream>>>(Wq, Wp, Wv, Wg, w_ih, w_hh, ws);
  prep_gemm<<<dim3(512, 24), 192, 0, stream>>>(uq, ws + OFF_WQST, ws + OFF_WUQA, 0);
  prep_gemm<<<dim3(512, 24), 192, 0, stream>>>(up, ws + OFF_WPST, ws + OFF_WUPALL, 1);
  pq_main<<<192, TMAIN, 0, stream>>>(up, uq, v0, V, b_ih, b_hh, ws, out);
}

// Round 2
// 20444.930 us; speedup vs baseline: 1.4740x; 1.4740x over previous
//
#include <hip/hip_runtime.h>
#include <hip/hip_fp16.h>

// Problem constants
#define NSTEP 512   // LP
#define NL    512   // LQ
#define NB    24
#define NH    150
#define TMAIN 512   // threads per main block

// ---- ws layout (float offsets) ----
#define OFF_WUQA   (0u)                              // __half region: [b][l][h] 2*WUq, 24*512*150 halfs
#define OFF_WUPALL (OFF_WUQA   + 24u*512u*150u)      // float [i][b][h] 512*24*150
#define OFF_WQST   (OFF_WUPALL + 512u*24u*150u)      // [d][h] 150*150 (fp32, for prep_gemm)
#define OFF_WPST   (OFF_WQST   + 22500u)
#define OFF_WVT    (OFF_WPST   + 22500u)             // [h'][h] 150*150 fp32
#define OFF_G1T    (OFF_WVT    + 22500u)             // [d][j'] 150*300 fp32
#define OFF_G2T    (OFF_G1T    + 45000u)
#define OFF_WIHT   (OFF_G2T    + 45000u)             // [d'][j] 300*450 fp32
#define OFF_WHHT   (OFF_WIHT   + 135000u)            // [h'][j] 150*450 fp32
#define OFF_S      (OFF_WHHT   + 67500u)             // [b][l] 24*512
#define OFF_CP     (OFF_S      + 12288u)             // [k][b][152]
#define OFF_GH     (OFF_CP     + 8u*24u*152u)        // [parity][b][456] (double-buffered)
#define OFF_GI     (OFF_GH     + 2u*24u*456u)        // [k][b][456]
#define OFF_BAR    (OFF_GI     + 8u*24u*456u)        // 800 uints: [32 + b*32] = group counter (own 128B line)
#define WS_FLOATS  (OFF_BAR + 800u)

__device__ __forceinline__ float fast_rcp(float x) { return __builtin_amdgcn_rcpf(x); }

// tanh(x) = 1 - 2/(e^{2x}+1); exp overflow->inf->rcp->0 => +1, underflow->0 => -1 (naturally saturating)
__device__ __forceinline__ float fast_tanh(float x) {
  return 1.f - 2.f * fast_rcp(__expf(2.f * x) + 1.f);
}
__device__ __forceinline__ float fast_sigmoid(float x) {
  return fast_rcp(1.f + __expf(-x));
}

// ---- cross-block exchange: relaxed agent-scope atomics (bypass to coherence point) ----
__device__ __forceinline__ void xstore(float* p, float v) {
  __hip_atomic_store(p, v, __ATOMIC_RELAXED, __HIP_MEMORY_SCOPE_AGENT);
}
__device__ __forceinline__ float xload(const float* p) {
  return __hip_atomic_load(p, __ATOMIC_RELAXED, __HIP_MEMORY_SCOPE_AGENT);
}

// Per-group barrier: 8 blocks of one batch-group only. Monotonic counter on a
// private 128B line. RELEASE on arrival (orders prior stores to the coherence
// point); polling stays RELAXED and there is NO acquire — all exchanged data is
// read via bypassing atomic loads, so no L1/L2 invalidation is needed and the
// L2-resident weights/WUq stay cached across barriers.
__device__ __forceinline__ void group_barrier(unsigned* gbar, unsigned& gen) {
  __builtin_amdgcn_s_waitcnt(0);   // drain this thread's vmem before signalling
  __syncthreads();
  if (threadIdx.x == 0) {
    gen += 8u;
    __hip_atomic_fetch_add(gbar, 1u, __ATOMIC_RELEASE, __HIP_MEMORY_SCOPE_AGENT);
    while (__hip_atomic_load(gbar, __ATOMIC_RELAXED, __HIP_MEMORY_SCOPE_AGENT) < gen) {
      __builtin_amdgcn_s_sleep(1);
    }
  }
  __syncthreads();
}

// ---------- prep: collapsed/transposed weights + barrier zeroing ----------
__global__ void prep_weights(const float* __restrict__ Wq, const float* __restrict__ Wp,
                             const float* __restrict__ Wv, const float* __restrict__ Wg,
                             const float* __restrict__ w_ih, const float* __restrict__ w_hh,
                             float* __restrict__ ws) {
  float* wqsT = ws + OFF_WQST;
  float* wpsT = ws + OFF_WPST;
  float* wvT  = ws + OFF_WVT;
  float* g1T  = ws + OFF_G1T;
  float* g2T  = ws + OFF_G2T;
  float* wihT = ws + OFF_WIHT;
  float* whhT = ws + OFF_WHHT;
  unsigned* bar = (unsigned*)(ws + OFF_BAR);

  int idx = blockIdx.x * blockDim.x + threadIdx.x;
  int n = gridDim.x * blockDim.x;

  for (int i = idx; i < 800; i += n) bar[i] = 0u;

  for (int i = idx; i < 150 * 150; i += n) {
    int d = i / 150, h = i - d * 150;
    wqsT[i] = Wq[h * 300 + d] + Wq[h * 300 + d + 150];
    wpsT[i] = Wp[h * 300 + d] + Wp[h * 300 + d + 150];
    wvT[i]  = Wv[h * 150 + d];
  }
  for (int i = idx; i < 150 * 300; i += n) {
    int d = i / 300, j = i - d * 300;
    int row = (300 + j) * 600;
    g1T[i] = Wg[row + d] + Wg[row + d + 150];        // up-part of collapsed Wg
    g2T[i] = Wg[row + 300 + d] + Wg[row + 450 + d];  // c-part
  }
  for (int i = idx; i < 300 * 450; i += n) {
    int d = i / 450, j = i - d * 450;
    wihT[i] = w_ih[j * 300 + d];
  }
  for (int i = idx; i < 150 * 450; i += n) {
    int d = i / 450, j = i - d * 450;
    whhT[i] = w_hh[j * 150 + d];
  }
}

// mode 0: out_half[(b*512+l)*150+h] = 2 * (x(l,b,:) @ wT)   (pre-scaled WUq for tanh trick)
// mode 1: out_f  [(l*24+b)*150+h]  =      x(l,b,:) @ wT
__global__ __launch_bounds__(192) void prep_gemm(const float* __restrict__ x,
                                                 const float* __restrict__ wT,
                                                 float* __restrict__ outp, int mode) {
  const int l = blockIdx.x, b = blockIdx.y;
  __shared__ float sx[152];
  const int tid = threadIdx.x;
  if (tid < 150) sx[tid] = x[((size_t)l * 24 + b) * 150 + tid];
  __syncthreads();
  if (tid < 150) {
    float acc = 0.f;
    for (int d = 0; d < 150; ++d) acc += sx[d] * wT[d * 150 + tid];
    if (mode == 0) ((__half*)outp)[((size_t)b * 512 + l) * 150 + tid] = __float2half(2.f * acc);
    else           outp[((size_t)l * 24 + b) * 150 + tid] = acc;
  }
}

// ---------- main persistent kernel: 24 groups x 8 blocks ----------
__global__ __launch_bounds__(TMAIN) void pq_main(
    const float* __restrict__ up, const float* __restrict__ uq,
    const float* __restrict__ v0, const float* __restrict__ Vfull,
    const float* __restrict__ b_ih, const float* __restrict__ b_hh,
    float* __restrict__ ws, float* __restrict__ out) {
  const int tid = threadIdx.x;
  const int gid = blockIdx.x;
  const int b = gid % 24;   // group: all 8 blocks of b land on XCD b%8 (perf heuristic only)
  const int k = gid / 24;   // 0..7, owns l-chunk [k*64, k*64+64)

  const __half* wuqa_h = (const __half*)(ws + OFF_WUQA);
  const float* wupall = ws + OFF_WUPALL;
  const float* wvT    = ws + OFF_WVT;
  const float* g1T    = ws + OFF_G1T;
  const float* g2T    = ws + OFF_G2T;
  const float* wihT   = ws + OFF_WIHT;
  const float* whhT   = ws + OFF_WHHT;
  float* ws_s  = ws + OFF_S;
  float* ws_cp = ws + OFF_CP;
  float* ws_gh = ws + OFF_GH;
  float* ws_gi = ws + OFF_GI;
  unsigned* gbar = ((unsigned*)(ws + OFF_BAR)) + 32 + b * 32;

  __shared__ __half sWUq2[64 * 150]; // own l-chunk of 2*WUq (resident all 512 steps)
  __shared__ __half sUq[64 * 150];   // own l-chunk of uq
  __shared__ float sV[152];          // Vv
  __shared__ float sVl[152];         // v state (redundant per block)
  __shared__ float sY2[152];         // 2*(Wup_i + Wvv)
  __shared__ float sYp[304];
  __shared__ float sUp[152];         // up_i
  __shared__ float sC[152];          // combined c150
  __shared__ float sA[64];           // softmax weights for own chunk
  __shared__ float sGI[456];
  __shared__ float sGH[456];
  __shared__ float sCp[40];          // own c_ range
  __shared__ float sRed[16];
  __shared__ float sGHp[232];
  __shared__ float sSumV;

  // INIT: stage chunks into LDS (once)
  {
    const __half* src = wuqa_h + ((size_t)b * 512 + (size_t)k * 64) * 150;
    for (int idx = tid; idx < 64 * 150; idx += TMAIN) sWUq2[idx] = src[idx];
    for (int idx = tid; idx < 64 * 150; idx += TMAIN) {
      int l = idx / 150, d = idx - l * 150;
      sUq[idx] = __float2half(uq[((k * 64 + l) * 24 + b) * 150 + d]);
    }
    for (int h = tid; h < 150; h += TMAIN) sV[h] = Vfull[b * 150 + h];
  }
  __syncthreads();
  if (tid == 0) {
    float s = 0.f;
    for (int h = 0; h < 150; ++h) s += sV[h];
    sSumV = s;
  }
  __syncthreads();

  unsigned gen = 0;

  for (int i = 0; i <= NSTEP; ++i) {
    // ---- segA: combine gi/gh -> GRU -> v; then y2, gh, s-chunk ----
    if (i == 0) {
      if (tid < 150) sVl[tid] = v0[b * 150 + tid];
    } else {
      if (tid < 450) {
        float acc = b_ih[tid];
        #pragma unroll
        for (int kk = 0; kk < 8; ++kk) acc += xload(&ws_gi[(kk * 24 + b) * 456 + tid]);
        sGI[tid] = acc;
        sGH[tid] = xload(&ws_gh[(((i - 1) & 1) * 24 + b) * 456 + tid]);
      }
    }
    __syncthreads();
    if (i > 0 && tid < 150) {
      const int h = tid;
      float rg = fast_sigmoid(sGI[h] + sGH[h]);
      float zg = fast_sigmoid(sGI[150 + h] + sGH[150 + h]);
      float nn = fast_tanh(sGI[300 + h] + rg * sGH[300 + h]);
      float vn = (1.f - zg) * nn + zg * sVl[h];
      sVl[h] = vn;
      if (k == 0) out[((size_t)(i - 1) * 24 + b) * 150 + h] = vn;
    }
    __syncthreads();
    if (i == NSTEP) break;

    // y partials (redundant per block) + load up_i
    if (tid < 300) {
      const int h = tid >> 1, half = tid & 1;
      const int hp0 = half * 75;
      float acc = 0.f;
      for (int hp = hp0; hp < hp0 + 75; ++hp) acc += sVl[hp] * wvT[hp * 150 + h];
      sYp[tid] = acc;
    } else if (tid >= 320 && tid < 470) {
      sUp[tid - 320] = up[((size_t)i * 24 + b) * 150 + (tid - 320)];
    }
    __syncthreads();
    // combine y2; gh partials = v_i @ w_hh^T for own j-range (57 per block)
    if (tid < 150) {
      sY2[tid] = 2.f * (wupall[((size_t)i * 24 + b) * 150 + tid] + sYp[2 * tid] + sYp[2 * tid + 1]);
    } else if (tid >= 256 && tid < 484) {
      const int idx = tid - 256;
      const int q = idx / 57, jl = idx - q * 57;
      const int j = k * 57 + jl;
      float acc = 0.f;
      if (j < 450) {
        const int h1 = q * 38;
        const int h2 = (h1 + 38 < 150) ? h1 + 38 : 150;
        for (int hp = h1; hp < h2; ++hp) acc += sVl[hp] * whhT[hp * 450 + j];
      }
      sGHp[idx] = acc;
    }
    __syncthreads();
    if (tid < 57) {
      const int j = k * 57 + tid;
      if (j < 450)
        xstore(&ws_gh[((i & 1) * 24 + b) * 456 + j],
               sGHp[tid] + sGHp[57 + tid] + sGHp[114 + tid] + sGHp[171 + tid] + b_hh[j]);
    }

    // ---- P1: s[b,l] = sumV - 2*sum_h V[h]*rcp(exp(2(WUq+y))+1) for own 64 l's ----
    {
      const int w = tid >> 6, lane = tid & 63;
      for (int ll = w * 8; ll < w * 8 + 8; ++ll) {
        float acc = 0.f;
        for (int h = lane; h < 150; h += 64) {
          float arg2 = __half2float(sWUq2[ll * 150 + h]) + sY2[h];
          acc += sV[h] * fast_rcp(__expf(arg2) + 1.f);
        }
        #pragma unroll
        for (int off = 32; off; off >>= 1) acc += __shfl_xor(acc, off, 64);
        if (lane == 0) xstore(&ws_s[b * 512 + k * 64 + ll], sSumV - 2.f * acc);
      }
    }
    group_barrier(gbar, gen);  // BAR1: s complete

    // ---- segB: softmax (redundant) + c-partial over own l-chunk ----
    {
      float sv = xload(&ws_s[b * 512 + tid]);
      float m = sv;
      #pragma unroll
      for (int off = 32; off; off >>= 1) m = fmaxf(m, __shfl_xor(m, off, 64));
      if ((tid & 63) == 0) sRed[tid >> 6] = m;
      __syncthreads();
      m = sRed[0];
      #pragma unroll
      for (int w2 = 1; w2 < 8; ++w2) m = fmaxf(m, sRed[w2]);
      __syncthreads();
      float e = __expf(sv - m);
      float zs = e;
      #pragma unroll
      for (int off = 32; off; off >>= 1) zs += __shfl_xor(zs, off, 64);
      if ((tid & 63) == 0) sRed[tid >> 6] = zs;
      __syncthreads();
      zs = 0.f;
      #pragma unroll
      for (int w2 = 0; w2 < 8; ++w2) zs += sRed[w2];
      float a = e * fast_rcp(zs);
      if (tid >= k * 64 && tid < k * 64 + 64) sA[tid - k * 64] = a;
      __syncthreads();
      if (tid < 150) {
        float acc = 0.f;
        for (int ll = 0; ll < 64; ++ll) acc += sA[ll] * __half2float(sUq[ll * 150 + tid]);
        xstore(&ws_cp[(k * 24 + b) * 152 + tid], acc);
      }
    }
    group_barrier(gbar, gen);  // BAR2: c partials complete

    // ---- segC: combine c, g (own 38 j'), c_, gi-partials over own d-range ----
    {
      if (tid < 150) {
        float acc = 0.f;
        #pragma unroll
        for (int kk = 0; kk < 8; ++kk) acc += xload(&ws_cp[(kk * 24 + b) * 152 + tid]);
        sC[tid] = acc;
      }
      __syncthreads();
      if (tid < 152) {
        const int jl = tid >> 2, qq = tid & 3;
        const int jp = k * 38 + jl;
        float acc = 0.f;
        if (jp < 300) {
          const float* W = (qq < 2) ? g1T : g2T;
          const float* X = (qq < 2) ? sUp : sC;
          const int d0 = (qq & 1) * 75;
          for (int d = d0; d < d0 + 75; ++d) acc += X[d] * W[d * 300 + jp];
        }
        sGHp[tid] = acc;
      }
      __syncthreads();
      if (tid < 38) {
        const int jp = k * 38 + tid;
        float cv = 0.f;
        if (jp < 300) {
          float x = sGHp[4 * tid] + sGHp[4 * tid + 1] + sGHp[4 * tid + 2] + sGHp[4 * tid + 3];
          float gg = fast_sigmoid(x);
          const int cidx = (jp >= 150) ? jp - 150 : jp;
          cv = gg * sC[cidx];
        }
        sCp[tid] = cv;
      }
      __syncthreads();
      if (tid < 450) {
        const int nd = (k < 7) ? 38 : 34;  // 300 - 7*38
        const int d0 = k * 38;
        float acc = 0.f;
        for (int dd = 0; dd < nd; ++dd) acc += sCp[dd] * wihT[(d0 + dd) * 450 + tid];
        xstore(&ws_gi[(k * 24 + b) * 456 + tid], acc);
      }
    }
    group_barrier(gbar, gen);  // BAR3: gi partials complete
  }
}

extern "C" void kernel_launch(void* const* d_in, const int* in_sizes, int n_in,
                              void* d_out, int out_size, void* d_ws, size_t ws_size,
                              hipStream_t stream) {
  const float* up   = (const float*)d_in[0];
  const float* uq   = (const float*)d_in[1];
  const float* v0   = (const float*)d_in[2];
  const float* V    = (const float*)d_in[3];
  const float* Wp   = (const float*)d_in[4];
  const float* Wq   = (const float*)d_in[5];
  const float* Wv   = (const float*)d_in[6];
  const float* Wg   = (const float*)d_in[7];
  const float* w_ih = (const float*)d_in[8];
  const float* w_hh = (const float*)d_in[9];
  const float* b_ih = (const float*)d_in[10];
  const float* b_hh = (const float*)d_in[11];
  float* ws  = (float*)d_ws;
  float* out = (float*)d_out;

  if (ws_size < (size_t)WS_FLOATS * sizeof(float)) return;

  prep_weights<<<256, 256, 0, stream>>>(Wq, Wp, Wv, Wg, w_ih, w_hh, ws);
  prep_gemm<<<dim3(512, 24), 192, 0, stream>>>(uq, ws + OFF_WQST, ws + OFF_WUQA, 0);
  prep_gemm<<<dim3(512, 24), 192, 0, stream>>>(up, ws + OFF_WPST, ws + OFF_WUPALL, 1);
  pq_main<<<192, TMAIN, 0, stream>>>(up, uq, v0, V, b_ih, b_hh, ws, out);
}

// Round 3
// 14833.936 us; speedup vs baseline: 2.0315x; 1.3783x over previous
//
#include <hip/hip_runtime.h>
#include <hip/hip_fp16.h>

typedef _Float16 half2_t __attribute__((ext_vector_type(2)));

// ---- ws layout (float-word offsets) ----
#define OFF_EW     0u                        // half[24][512][160]: exp(2*WUq), pads=1.0
#define OFF_UQT    983040u                   // half[24][152][512]: Uq^T per b (rows d<150 used)
#define OFF_WUP2   1916928u                  // f32 [512][24][152]: 2*Wup, pads=0
#define OFF_WA     3784704u                  // half[600][160]: rows<150 Wv, rows 150+ w_hh; pads=0
#define OFF_WG     3832704u                  // half[304][320]: collapsed Wg rows 300..599; pads=0
#define OFF_WIH    3881344u                  // half[456][320]: w_ih; pads=0
#define OFF_WQST   3954304u                  // f32 [150][150] collapsed Wq^T
#define OFF_WPST   3976804u                  // f32 [150][150] collapsed Wp^T
#define WS_FLOATS  3999304u                  // ~16.0 MB

__device__ __forceinline__ float fast_rcp(float x) { return __builtin_amdgcn_rcpf(x); }
__device__ __forceinline__ float fast_tanh(float x) {
  return 1.f - 2.f * fast_rcp(__expf(2.f * x) + 1.f);   // saturates correctly at +/-inf
}
__device__ __forceinline__ float fast_sigmoid(float x) {
  return fast_rcp(1.f + __expf(-x));
}

#if defined(__has_builtin)
#if __has_builtin(__builtin_amdgcn_fdot2)
#define HAVE_FDOT2 1
#endif
#endif
__device__ __forceinline__ float fdot2(half2_t a, half2_t b, float c) {
#ifdef HAVE_FDOT2
  return __builtin_amdgcn_fdot2(a, b, c, false);
#else
  return c + (float)a.x * (float)b.x + (float)a.y * (float)b.y;
#endif
}

// ---------- prep: collapsed/transposed fp16 weights ----------
__global__ void prep_weights(const float* __restrict__ Wq, const float* __restrict__ Wp,
                             const float* __restrict__ Wv, const float* __restrict__ Wg,
                             const float* __restrict__ w_ih, const float* __restrict__ w_hh,
                             float* __restrict__ ws) {
  float* wqsT = ws + OFF_WQST;
  float* wpsT = ws + OFF_WPST;
  _Float16* WA  = (_Float16*)(ws + OFF_WA);
  _Float16* WG  = (_Float16*)(ws + OFF_WG);
  _Float16* WIH = (_Float16*)(ws + OFF_WIH);

  int idx = blockIdx.x * blockDim.x + threadIdx.x;
  int n = gridDim.x * blockDim.x;

  for (int i = idx; i < 150 * 150; i += n) {
    int d = i / 150, h = i - d * 150;
    wqsT[i] = Wq[h * 300 + d] + Wq[h * 300 + d + 150];
    wpsT[i] = Wp[h * 300 + d] + Wp[h * 300 + d + 150];
  }
  for (int i = idx; i < 600 * 160; i += n) {
    int r = i / 160, hp = i - r * 160;
    float v = 0.f;
    if (hp < 150) v = (r < 150) ? Wv[r * 150 + hp] : w_hh[(r - 150) * 150 + hp];
    WA[i] = (_Float16)v;
  }
  for (int i = idx; i < 304 * 320; i += n) {
    int j = i / 320, d = i - j * 320;
    float v = 0.f;
    if (j < 300) {
      int row = (300 + j) * 600;
      if (d < 150)                 v = Wg[row + d] + Wg[row + 150 + d];
      else if (d >= 160 && d < 310) v = Wg[row + 300 + (d - 160)] + Wg[row + 450 + (d - 160)];
    }
    WG[i] = (_Float16)v;
  }
  for (int i = idx; i < 456 * 320; i += n) {
    int j = i / 320, d = i - j * 320;
    float v = (j < 450 && d < 300) ? w_ih[j * 300 + d] : 0.f;
    WIH[i] = (_Float16)v;
  }
}

// EW[b][l][h] = clamp(exp(2 * uq_l,b . wqsT[:,h]), 1e-7, 6e4) as half; pads h>=150 -> 1.0
__global__ __launch_bounds__(192) void prep_ew(const float* __restrict__ uq, float* __restrict__ ws) {
  const float* wqsT = ws + OFF_WQST;
  _Float16* EW = (_Float16*)(ws + OFF_EW);
  const int l = blockIdx.x, b = blockIdx.y;
  __shared__ float sx[150];
  const int t = threadIdx.x;
  if (t < 150) sx[t] = uq[((size_t)l * 24 + b) * 150 + t];
  __syncthreads();
  if (t < 160) {
    float val = 1.f;
    if (t < 150) {
      float acc = 0.f;
      for (int d = 0; d < 150; ++d) acc += sx[d] * wqsT[d * 150 + t];
      val = __expf(2.f * acc);
      val = fminf(fmaxf(val, 1e-7f), 60000.f);   // keep EW finite-positive in half
    }
    EW[((size_t)b * 512 + l) * 160 + t] = (_Float16)val;
  }
}

// WUP2[i][b][h] = 2 * up_i,b . wpsT[:,h] (f32), pads h>=150 -> 0
__global__ __launch_bounds__(192) void prep_wup2(const float* __restrict__ up, float* __restrict__ ws) {
  const float* wpsT = ws + OFF_WPST;
  float* WUP2 = ws + OFF_WUP2;
  const int l = blockIdx.x, b = blockIdx.y;
  __shared__ float sx[150];
  const int t = threadIdx.x;
  if (t < 150) sx[t] = up[((size_t)l * 24 + b) * 150 + t];
  __syncthreads();
  if (t < 152) {
    float val = 0.f;
    if (t < 150) {
      float acc = 0.f;
      for (int d = 0; d < 150; ++d) acc += sx[d] * wpsT[d * 150 + t];
      val = 2.f * acc;
    }
    WUP2[((size_t)l * 24 + b) * 152 + t] = val;
  }
}

// UQT[b][d][l] = uq[l][b][d] as half (rows d<150)
__global__ void prep_uqt(const float* __restrict__ uq, float* __restrict__ ws) {
  _Float16* UQT = (_Float16*)(ws + OFF_UQT);
  int idx = blockIdx.x * blockDim.x + threadIdx.x;
  int n = gridDim.x * blockDim.x;
  for (int m = idx; m < 24 * 150 * 512; m += n) {
    int b = m / (150 * 512);
    int rem = m - b * 150 * 512;
    int d = rem >> 9;
    int l = rem & 511;
    UQT[((size_t)b * 152 + d) * 512 + l] = (_Float16)uq[((size_t)l * 24 + b) * 150 + d];
  }
}

// ---------- main: 24 blocks (one per b) x 1024 threads, __syncthreads only ----------
__global__ __launch_bounds__(1024) void pq_main(
    const float* __restrict__ up, const float* __restrict__ v0,
    const float* __restrict__ Vfull, const float* __restrict__ b_ih,
    const float* __restrict__ b_hh, const float* __restrict__ ws,
    float* __restrict__ out) {
  const int tid = threadIdx.x;
  const int b = blockIdx.x;

  const _Float16* EW   = (const _Float16*)(ws + OFF_EW);
  const _Float16* UQT  = (const _Float16*)(ws + OFF_UQT);
  const float*    WUP2 = ws + OFF_WUP2;
  const _Float16* WA   = (const _Float16*)(ws + OFF_WA);
  const _Float16* WG   = (const _Float16*)(ws + OFF_WG);
  const _Float16* WIH  = (const _Float16*)(ws + OFF_WIH);

  __shared__ float sVl[152], sV[160], sEy[160], sWup2[152], sTmpA[600],
                   sGH[456], sGip[456], sS[512], sC[152], sBih[456], sBhh[456],
                   sRed[8], sRedB[8];
  __shared__ float sSumV;
  __shared__ half2_t sVh2[80], sXh2[160], sCph2[160], sAhc2[264];
  _Float16* sVh  = (_Float16*)sVh2;
  _Float16* sXh  = (_Float16*)sXh2;
  _Float16* sCph = (_Float16*)sCph2;
  _Float16* sAhc = (_Float16*)sAhc2;

  // ---- init ----
  if (tid < 152) sVl[tid] = (tid < 150) ? v0[b * 150 + tid] : 0.f;
  if (tid < 160) {
    sV[tid]  = (tid < 150) ? Vfull[b * 150 + tid] : 0.f;
    sVh[tid] = (tid < 150) ? (_Float16)v0[b * 150 + tid] : (_Float16)0.f;
  }
  if (tid < 320) { sXh[tid] = (_Float16)0.f; sCph[tid] = (_Float16)0.f; }
  if (tid < 456) {
    sBih[tid] = (tid < 450) ? b_ih[tid] : 0.f;
    sBhh[tid] = (tid < 450) ? b_hh[tid] : 0.f;
  }
  __syncthreads();
  if (tid < 64) {
    float s = 0.f;
    for (int h = tid; h < 150; h += 64) s += sV[h];
    #pragma unroll
    for (int off = 32; off; off >>= 1) s += __shfl_xor(s, off, 64);
    if (tid == 0) sSumV = s;
  }
  __syncthreads();

  for (int i = 0; i < 512; ++i) {
    // ---- A: tmpA = [Wv; Whh] @ v  (fp16 fdot2); loaders fetch Wup2_i, up_i ----
    if (tid < 600) {
      const half2_t* pw = (const half2_t*)(WA + (size_t)tid * 160);
      float acc = 0.f;
      #pragma unroll
      for (int k = 0; k < 80; ++k) acc = fdot2(pw[k], sVh2[k], acc);
      sTmpA[tid] = acc;
    } else if (tid >= 640 && tid < 792) {
      int h = tid - 640;
      sWup2[h] = WUP2[((size_t)i * 24 + b) * 152 + h];
    } else if (tid >= 800 && tid < 950) {
      int d = tid - 800;
      sXh[d] = (_Float16)up[((size_t)i * 24 + b) * 150 + d];
    }
    __syncthreads();
    // ---- A2: ey = exp(2*(Wup + Wvv)); gh = Whh@v + b_hh ----
    if (tid < 160) {
      float v = 1.f;
      if (tid < 150) v = __expf(sWup2[tid] + 2.f * sTmpA[tid]);
      sEy[tid] = v;
    } else if (tid >= 192 && tid < 642) {
      int j = tid - 192;
      sGH[j] = sTmpA[150 + j] + sBhh[j];
    }
    __syncthreads();
    // ---- P1: s[l] = sumV - 2*sum_h V[h]*rcp(EW[l][h]*ey[h] + 1) ----
    {
      const int lg = tid >> 3, hc = tid & 7;   // 128 l-groups of 4, 8 h-chunks of 20
      float ey[20], vv[20];
      #pragma unroll
      for (int j2 = 0; j2 < 20; ++j2) { ey[j2] = sEy[hc * 20 + j2]; vv[j2] = sV[hc * 20 + j2]; }
      const _Float16* EWb = EW + ((size_t)b * 512 + (size_t)lg * 4) * 160 + hc * 20;
      float acc[4];
      #pragma unroll
      for (int r = 0; r < 4; ++r) {
        const half2_t* pe = (const half2_t*)(EWb + (size_t)r * 160);
        float a = 0.f;
        #pragma unroll
        for (int k = 0; k < 10; ++k) {
          half2_t ew = pe[k];
          a += vv[2 * k]     * fast_rcp((float)ew.x * ey[2 * k]     + 1.f);
          a += vv[2 * k + 1] * fast_rcp((float)ew.y * ey[2 * k + 1] + 1.f);
        }
        acc[r] = a;
      }
      #pragma unroll
      for (int off = 1; off <= 4; off <<= 1) {
        #pragma unroll
        for (int r = 0; r < 4; ++r) acc[r] += __shfl_xor(acc[r], off, 64);
      }
      if (hc == 0) {
        #pragma unroll
        for (int r = 0; r < 4; ++r) sS[lg * 4 + r] = sSumV - 2.f * acc[r];
      }
    }
    __syncthreads();
    // ---- SM: softmax over 512, result as half pairs (chunk-padded 64->66) ----
    {
      const bool act = tid < 512;
      float sv = act ? sS[tid] : -3.4e38f;
      float m = sv;
      #pragma unroll
      for (int off = 32; off; off >>= 1) m = fmaxf(m, __shfl_xor(m, off, 64));
      if (act && (tid & 63) == 0) sRed[tid >> 6] = m;
      __syncthreads();
      m = sRed[0];
      #pragma unroll
      for (int w = 1; w < 8; ++w) m = fmaxf(m, sRed[w]);
      float e = act ? __expf(sv - m) : 0.f;
      float z = e;
      #pragma unroll
      for (int off = 32; off; off >>= 1) z += __shfl_xor(z, off, 64);
      if (act && (tid & 63) == 0) sRedB[tid >> 6] = z;
      __syncthreads();
      z = 0.f;
      #pragma unroll
      for (int w = 0; w < 8; ++w) z += sRedB[w];
      if (act) {
        float a = e * fast_rcp(z);
        int p = tid >> 1;
        sAhc[(p >> 6) * 132 + (p & 63) * 2 + (tid & 1)] = (_Float16)a;
      }
    }
    __syncthreads();
    // ---- P2: c[d] = sum_l a[l] * Uq[l][d]  (fdot2 over l; quad-split, shfl combine) ----
    if (tid < 608) {
      const int d = tid >> 2, lc = tid & 3;
      float acc = 0.f;
      if (d < 150) {
        const half2_t* pu = (const half2_t*)(UQT + ((size_t)b * 152 + d) * 512) + lc * 64;
        const half2_t* pa = (const half2_t*)(sAhc + lc * 132);
        #pragma unroll
        for (int k = 0; k < 64; ++k) acc = fdot2(pa[k], pu[k], acc);
      }
      acc += __shfl_xor(acc, 1, 64);
      acc += __shfl_xor(acc, 2, 64);
      if (lc == 0 && d < 150) { sC[d] = acc; sXh[160 + d] = (_Float16)acc; }
    }
    __syncthreads();
    // ---- P3: g = sigmoid(WG @ [up;c]); c_ = g * c_expand  (pair-split, shfl combine) ----
    if (tid < 608) {
      const int j = tid >> 1, sp = tid & 1;
      float acc = 0.f;
      if (j < 300) {
        const half2_t* pw = (const half2_t*)(WG + (size_t)j * 320) + sp * 80;
        const half2_t* px = sXh2 + sp * 80;
        #pragma unroll
        for (int k = 0; k < 80; ++k) acc = fdot2(pw[k], px[k], acc);
      }
      acc += __shfl_xor(acc, 1, 64);
      if (sp == 0 && j < 300) {
        float g = fast_sigmoid(acc);
        int cj = (j >= 150) ? j - 150 : j;
        sCph[j] = (_Float16)(g * sC[cj]);
      }
    }
    __syncthreads();
    // ---- P4: gi = WIH @ c_  (pair-split, shfl combine) ----
    if (tid < 912) {
      const int j = tid >> 1, sp = tid & 1;
      float acc = 0.f;
      if (j < 450) {
        const half2_t* pw = (const half2_t*)(WIH + (size_t)j * 320) + sp * 80;
        const half2_t* px = sCph2 + sp * 80;
        #pragma unroll
        for (int k = 0; k < 80; ++k) acc = fdot2(pw[k], px[k], acc);
      }
      acc += __shfl_xor(acc, 1, 64);
      if (sp == 0 && j < 450) sGip[j] = acc;
    }
    __syncthreads();
    // ---- GRU ----
    if (tid < 150) {
      const int h = tid;
      float gir = sGip[h]       + sBih[h];
      float giz = sGip[150 + h] + sBih[150 + h];
      float gin = sGip[300 + h] + sBih[300 + h];
      float rg = fast_sigmoid(gir + sGH[h]);
      float zg = fast_sigmoid(giz + sGH[150 + h]);
      float nn = fast_tanh(gin + rg * sGH[300 + h]);
      float vn = (1.f - zg) * nn + zg * sVl[h];
      sVl[h] = vn;
      sVh[h] = (_Float16)vn;
      out[((size_t)i * 24 + b) * 150 + h] = vn;
    }
    __syncthreads();
  }
}

extern "C" void kernel_launch(void* const* d_in, const int* in_sizes, int n_in,
                              void* d_out, int out_size, void* d_ws, size_t ws_size,
                              hipStream_t stream) {
  const float* up   = (const float*)d_in[0];
  const float* uq   = (const float*)d_in[1];
  const float* v0   = (const float*)d_in[2];
  const float* V    = (const float*)d_in[3];
  const float* Wp   = (const float*)d_in[4];
  const float* Wq   = (const float*)d_in[5];
  const float* Wv   = (const float*)d_in[6];
  const float* Wg   = (const float*)d_in[7];
  const float* w_ih = (const float*)d_in[8];
  const float* w_hh = (const float*)d_in[9];
  const float* b_ih = (const float*)d_in[10];
  const float* b_hh = (const float*)d_in[11];
  float* ws  = (float*)d_ws;
  float* out = (float*)d_out;

  if (ws_size < (size_t)WS_FLOATS * sizeof(float)) return;

  prep_weights<<<256, 256, 0, stream>>>(Wq, Wp, Wv, Wg, w_ih, w_hh, ws);
  prep_uqt<<<512, 256, 0, stream>>>(uq, ws);
  prep_ew<<<dim3(512, 24), 192, 0, stream>>>(uq, ws);
  prep_wup2<<<dim3(512, 24), 192, 0, stream>>>(up, ws);
  pq_main<<<24, 1024, 0, stream>>>(up, v0, V, b_ih, b_hh, ws, out);
}